// Round 1
// baseline (585.422 us; speedup 1.0000x reference)
//
#include <hip/hip_runtime.h>

// Problem constants (match setup_inputs)
#define NN 50000      // nodes
#define NE 800000     // edges
#define DIN 256       // 192 + 64
#define DOUT 256

typedef __attribute__((ext_vector_type(8))) short bf16x8;  // 8 bf16 = 4 VGPRs
typedef __attribute__((ext_vector_type(4))) float f32x4;   // MFMA acc

__device__ __forceinline__ unsigned short f2bf(float x) {
    unsigned int u = __builtin_bit_cast(unsigned int, x);
    u += 0x7fffu + ((u >> 16) & 1u);        // round-to-nearest-even
    return (unsigned short)(u >> 16);
}
__device__ __forceinline__ float bf2f(unsigned short b) {
    return __builtin_bit_cast(float, ((unsigned int)b) << 16);
}

// ---------------------------------------------------------------------------
// ws layout (4-byte words):
//   h_bf     [NN*256]  bf16  (25.6 MB)
//   wt_bf    [256*256] bf16  (W transposed: wt[n][k]=W[k][n])
//   featn_bf [NN*192]  bf16  (19.2 MB; feat * odeg_inv, pre-rounded)
//   row_off  [NN+2]    int
//   odeg_inv [NN]      float
//   cursor   [NN]      int
//   bsum     [256]     int
//   perm2    [NE]      int2  (first 2*NN ints alias in_cnt/out_cnt early)
// ---------------------------------------------------------------------------

__global__ __launch_bounds__(256) void zero_meta(int* __restrict__ p, int n) {
    int i = blockIdx.x * 256 + threadIdx.x;
    if (i < n) p[i] = 0;
}

__global__ __launch_bounds__(256) void count_kernel(const int* __restrict__ src,
                                                    const int* __restrict__ dst,
                                                    int* __restrict__ in_cnt,
                                                    int* __restrict__ out_cnt) {
    int e = blockIdx.x * 256 + threadIdx.x;
    if (e < NE) {
        atomicAdd(in_cnt + dst[e], 1);
        atomicAdd(out_cnt + src[e], 1);
    }
}

__global__ __launch_bounds__(256) void scan1(const int* __restrict__ cnt,
                                             int* __restrict__ row_off,
                                             int* __restrict__ bsum) {
    __shared__ int tmp[256];
    int tid = threadIdx.x;
    int i = blockIdx.x * 256 + tid;
    int v = (i < NN) ? cnt[i] : 0;
    tmp[tid] = v;
    __syncthreads();
#pragma unroll
    for (int off = 1; off < 256; off <<= 1) {
        int t = (tid >= off) ? tmp[tid - off] : 0;
        __syncthreads();
        if (tid >= off) tmp[tid] += t;
        __syncthreads();
    }
    if (i < NN) row_off[i] = tmp[tid] - v;   // exclusive
    if (tid == 255) bsum[blockIdx.x] = tmp[255];
}

__global__ __launch_bounds__(256) void scan2(int* __restrict__ bsum, int nb) {
    __shared__ int tmp[256];
    int tid = threadIdx.x;
    int v = (tid < nb) ? bsum[tid] : 0;
    tmp[tid] = v;
    __syncthreads();
#pragma unroll
    for (int off = 1; off < 256; off <<= 1) {
        int t = (tid >= off) ? tmp[tid - off] : 0;
        __syncthreads();
        if (tid >= off) tmp[tid] += t;
        __syncthreads();
    }
    if (tid < nb) bsum[tid] = tmp[tid] - v;  // exclusive
}

// Finish row_off scan; seed cursor; fold in odeg_inv (out_cnt still live here).
__global__ __launch_bounds__(256) void scan3(int* __restrict__ row_off,
                                             int* __restrict__ cursor,
                                             float* __restrict__ odeg_inv,
                                             const int* __restrict__ out_cnt,
                                             const int* __restrict__ bsum) {
    int i = blockIdx.x * 256 + threadIdx.x;
    if (i < NN) {
        int v = row_off[i] + bsum[i >> 8];
        row_off[i] = v;
        cursor[i] = v;
        odeg_inv[i] = rsqrtf((float)max(out_cnt[i], 1));
    }
    if (i == NN) row_off[NN] = NE;
}

// W[k][n] fp32 -> wt[n][k] bf16
__global__ __launch_bounds__(256) void wconv(const float* __restrict__ W,
                                             unsigned short* __restrict__ wt) {
    int n = blockIdx.x, k = threadIdx.x;
    wt[n * 256 + k] = f2bf(W[k * 256 + n]);
}

// featn_bf[n][k] = bf16(feat[n][k] * odeg_inv[n]).  Halves gather bytes in
// aggregate and shrinks the gathered set to 19.2 MB (near L2-resident).
__global__ __launch_bounds__(256) void featconv(const float* __restrict__ feat,
                                                const float* __restrict__ odeg_inv,
                                                unsigned short* __restrict__ featn) {
    int node = blockIdx.x * 4 + (threadIdx.x >> 6);
    int lane = threadIdx.x & 63;
    if (node >= NN || lane >= 48) return;
    float s = odeg_inv[node];
    float4 v = *(const float4*)(feat + (size_t)node * 192 + lane * 4);
    ushort4 o;
    o.x = f2bf(v.x * s); o.y = f2bf(v.y * s);
    o.z = f2bf(v.z * s); o.w = f2bf(v.w * s);
    *(ushort4*)(featn + (size_t)node * 192 + lane * 4) = o;
}

// CSR fill: perm2[pos] = (edge id, src[e])
__global__ __launch_bounds__(256) void fill_kernel(const int* __restrict__ src,
                                                   const int* __restrict__ dst,
                                                   int* __restrict__ cursor,
                                                   int2* __restrict__ perm2) {
    int e = blockIdx.x * 256 + threadIdx.x;
    if (e < NE) {
        int d = dst[e];
        int pos = atomicAdd(cursor + d, 1);
        perm2[pos] = make_int2(e, src[e]);
    }
}

// One wave per dst node; lane owns one 4-col slice of the 256-wide h row.
// Lanes 0-47: feat part, bf16 gathers (8 B/lane), scale pre-applied.
// Lanes 48-63: edge part, f32 gathers (16 B/lane).
// fp32 accumulate, single bf16 round at store.
__global__ __launch_bounds__(256) void aggregate_kernel(const unsigned short* __restrict__ featn,
                                                        const float* __restrict__ edge_feat,
                                                        const int* __restrict__ row_off,
                                                        const int2* __restrict__ perm2,
                                                        unsigned short* __restrict__ h_bf) {
    int node = blockIdx.x * 4 + (threadIdx.x >> 6);
    int lane = threadIdx.x & 63;
    if (node >= NN) return;
    int start = row_off[node];
    int end   = row_off[node + 1];

    float4 acc = make_float4(0.f, 0.f, 0.f, 0.f);

    if (lane < 48) {
        const unsigned short* fb = featn + lane * 4;
        for (int i = start; i < end; i += 8) {
            int2 p[8];
#pragma unroll
            for (int j = 0; j < 8; ++j) p[j] = perm2[min(i + j, end - 1)];
            ushort4 u[8];
#pragma unroll
            for (int j = 0; j < 8; ++j)
                u[j] = *(const ushort4*)(fb + (size_t)p[j].y * 192);
#pragma unroll
            for (int j = 0; j < 8; ++j) {
                float w = (i + j < end) ? 1.f : 0.f;
                acc.x = fmaf(bf2f(u[j].x), w, acc.x);
                acc.y = fmaf(bf2f(u[j].y), w, acc.y);
                acc.z = fmaf(bf2f(u[j].z), w, acc.z);
                acc.w = fmaf(bf2f(u[j].w), w, acc.w);
            }
        }
    } else {
        const float* eb = edge_feat + (lane - 48) * 4;
        for (int i = start; i < end; i += 8) {
            int2 p[8];
#pragma unroll
            for (int j = 0; j < 8; ++j) p[j] = perm2[min(i + j, end - 1)];
            float4 v[8];
#pragma unroll
            for (int j = 0; j < 8; ++j)
                v[j] = *(const float4*)(eb + (size_t)p[j].x * 64);
#pragma unroll
            for (int j = 0; j < 8; ++j) {
                float w = (i + j < end) ? 1.f : 0.f;
                acc.x = fmaf(v[j].x, w, acc.x);
                acc.y = fmaf(v[j].y, w, acc.y);
                acc.z = fmaf(v[j].z, w, acc.z);
                acc.w = fmaf(v[j].w, w, acc.w);
            }
        }
    }

    ushort4 o;
    o.x = f2bf(acc.x); o.y = f2bf(acc.y);
    o.z = f2bf(acc.z); o.w = f2bf(acc.w);
    *(ushort4*)(h_bf + (size_t)node * 256 + lane * 4) = o;
}

// MFMA GEMM: out = (h_bf @ W) * rsqrt(max(in_deg,1))[:,None] + bias
// Block = 16 rows x 256 cols; 4 waves side-by-side on cols (64 each).
// Wave: 4 col-tiles of 16x16 over K=256 in 8 steps of k=32. No LDS.
// C/D: row = (lane>>4)*4 + reg, col = lane&15   [guide §3, m89-verified]
__global__ __launch_bounds__(256) void gemm_mfma(const unsigned short* __restrict__ h_bf,
                                                 const unsigned short* __restrict__ wt_bf,
                                                 const float* __restrict__ bias,
                                                 const int* __restrict__ row_off,
                                                 float* __restrict__ out) {
    int wave = threadIdx.x >> 6;
    int lane = threadIdx.x & 63;
    int m16  = lane & 15;
    int quad = lane >> 4;
    int rbase = blockIdx.x * 16;
    int cbase = wave * 64;

    const unsigned short* arow = h_bf + (size_t)(rbase + m16) * 256 + quad * 8;
    const unsigned short* b0p = wt_bf + (size_t)(cbase +  0 + m16) * 256 + quad * 8;
    const unsigned short* b1p = wt_bf + (size_t)(cbase + 16 + m16) * 256 + quad * 8;
    const unsigned short* b2p = wt_bf + (size_t)(cbase + 32 + m16) * 256 + quad * 8;
    const unsigned short* b3p = wt_bf + (size_t)(cbase + 48 + m16) * 256 + quad * 8;

    f32x4 acc0 = {0.f, 0.f, 0.f, 0.f};
    f32x4 acc1 = {0.f, 0.f, 0.f, 0.f};
    f32x4 acc2 = {0.f, 0.f, 0.f, 0.f};
    f32x4 acc3 = {0.f, 0.f, 0.f, 0.f};

#pragma unroll
    for (int k0 = 0; k0 < 256; k0 += 32) {
        bf16x8 a  = *(const bf16x8*)(arow + k0);
        bf16x8 b0 = *(const bf16x8*)(b0p + k0);
        bf16x8 b1 = *(const bf16x8*)(b1p + k0);
        bf16x8 b2 = *(const bf16x8*)(b2p + k0);
        bf16x8 b3 = *(const bf16x8*)(b3p + k0);
        acc0 = __builtin_amdgcn_mfma_f32_16x16x32_bf16(a, b0, acc0, 0, 0, 0);
        acc1 = __builtin_amdgcn_mfma_f32_16x16x32_bf16(a, b1, acc1, 0, 0, 0);
        acc2 = __builtin_amdgcn_mfma_f32_16x16x32_bf16(a, b2, acc2, 0, 0, 0);
        acc3 = __builtin_amdgcn_mfma_f32_16x16x32_bf16(a, b3, acc3, 0, 0, 0);
    }

    // in-degree scales for this lane's 4 output rows
    int grow0 = rbase + quad * 4;
    float s[4];
    int ro_prev = row_off[grow0];
#pragma unroll
    for (int r = 0; r < 4; ++r) {
        int nx = row_off[grow0 + r + 1];
        s[r] = rsqrtf((float)max(nx - ro_prev, 1));
        ro_prev = nx;
    }

    float bv0 = bias[cbase +  0 + m16];
    float bv1 = bias[cbase + 16 + m16];
    float bv2 = bias[cbase + 32 + m16];
    float bv3 = bias[cbase + 48 + m16];

#pragma unroll
    for (int r = 0; r < 4; ++r) {
        size_t rowoff = (size_t)(grow0 + r) * DOUT;
        out[rowoff + cbase +  0 + m16] = acc0[r] * s[r] + bv0;
        out[rowoff + cbase + 16 + m16] = acc1[r] * s[r] + bv1;
        out[rowoff + cbase + 32 + m16] = acc2[r] * s[r] + bv2;
        out[rowoff + cbase + 48 + m16] = acc3[r] * s[r] + bv3;
    }
}

extern "C" void kernel_launch(void* const* d_in, const int* in_sizes, int n_in,
                              void* d_out, int out_size, void* d_ws, size_t ws_size,
                              hipStream_t stream) {
    const float* feat      = (const float*)d_in[0];
    const float* edge_feat = (const float*)d_in[1];
    const int*   src       = (const int*)d_in[2];
    const int*   dst       = (const int*)d_in[3];
    const float* W         = (const float*)d_in[4];
    const float* bias      = (const float*)d_in[5];
    float* out = (float*)d_out;

    unsigned short* h_bf    = (unsigned short*)d_ws;                 // NN*256 bf16
    unsigned short* wt_bf   = h_bf + (size_t)NN * DIN;               // 256*256 bf16
    unsigned short* featn   = wt_bf + 256 * 256;                     // NN*192 bf16
    int*   row_off  = (int*)(featn + (size_t)NN * 192);              // NN+2
    float* odeg_inv = (float*)(row_off + NN + 2);                    // NN
    int*   cursor   = (int*)(odeg_inv + NN);                         // NN
    int*   bsum     = cursor + NN;                                   // 256
    int2*  perm2    = (int2*)(bsum + 256);                           // NE int2
    int*   in_cnt   = (int*)perm2;                                   // alias (early)
    int*   out_cnt  = in_cnt + NN;                                   // alias (early)

    const int SCAN_BLOCKS = (NN + 255) / 256;   // 196

    zero_meta<<<(2 * NN + 255) / 256, 256, 0, stream>>>(in_cnt, 2 * NN);
    count_kernel<<<(NE + 255) / 256, 256, 0, stream>>>(src, dst, in_cnt, out_cnt);
    scan1<<<SCAN_BLOCKS, 256, 0, stream>>>(in_cnt, row_off, bsum);
    scan2<<<1, 256, 0, stream>>>(bsum, SCAN_BLOCKS);
    scan3<<<(NN + 256) / 256, 256, 0, stream>>>(row_off, cursor, odeg_inv, out_cnt, bsum);
    wconv<<<256, 256, 0, stream>>>(W, wt_bf);
    featconv<<<(NN + 3) / 4, 256, 0, stream>>>(feat, odeg_inv, featn);
    fill_kernel<<<(NE + 255) / 256, 256, 0, stream>>>(src, dst, cursor, perm2);
    aggregate_kernel<<<(NN + 3) / 4, 256, 0, stream>>>(featn, edge_feat, row_off,
                                                       perm2, h_bf);
    gemm_mfma<<<NN / 16, 256, 0, stream>>>(h_bf, wt_bf, bias, row_off, out);
}